// Round 5
// baseline (43.841 us; speedup 1.0000x reference)
//
#include <hip/hip_runtime.h>

// out[n, h*28+w] = cos(pi * x[n,2h,2w] / (m[h,w] + 1e-8)),
// m[h,w] = max_n max(x[n,2h,2w], x[n,2h,2w+1]).
// (Unit-modulus phases + CNOT perm leave the Z0 expectation = cos(t0);
//  params/phases/permutation cancel exactly.)
//
// TWO dispatches, no atomics, no init pass:
//  A: 512 blocks x 16 images -> per-block partial maxima M[512][784]
//     (float4 loads over even rows, float2 plain stores).
//  B: 1792 blocks = 28 output-rows x 64 image-slices (128 images each).
//     Each block redundantly reduces its 28-col slice of M (56 KB, L2-hot)
//     in LDS -> mu for its row, then cos(p0 * 0.5/(m+eps)) via v_cos
//     (revolutions), contiguous 112B stores per image.

namespace {

constexpr int IMG  = 3136;   // 56*56 floats / image
constexpr int HW   = 784;    // 28*28 outputs / image
constexpr int NIMG = 8192;
constexpr int NB1  = 512;    // A blocks
constexpr int IPB  = NIMG / NB1;   // 16 images per A block
constexpr int IPB2 = 128;    // images per B block
constexpr int NSL  = NIMG / IPB2;  // 64 image-slices

__global__ __launch_bounds__(256) void k_partial(const float* __restrict__ x,
                                                 float* __restrict__ M) {
    const int t = threadIdx.x;
    const int b = blockIdx.x;

    // slot u covers float4 at row 2h, cols 4wq..4wq+3 = positions 2u, 2u+1
    const int h0 = t / 14,  w0 = t - h0 * 14,  o0 = h0 * 112 + w0 * 4;
    const int u1 = t + 256;
    const int h1 = u1 / 14, w1 = u1 - h1 * 14, o1 = h1 * 112 + w1 * 4;
    const bool a1 = (u1 < 392);

    float2 lm0 = make_float2(0.f, 0.f);
    float2 lm1 = make_float2(0.f, 0.f);

    const float* base = x + (size_t)b * IPB * IMG;
#pragma unroll 4
    for (int n = 0; n < IPB; ++n) {
        const float* p = base + (size_t)n * IMG;
        float4 v = *(const float4*)(p + o0);
        lm0.x = fmaxf(lm0.x, fmaxf(v.x, v.y));
        lm0.y = fmaxf(lm0.y, fmaxf(v.z, v.w));
        if (a1) {
            float4 w = *(const float4*)(p + o1);
            lm1.x = fmaxf(lm1.x, fmaxf(w.x, w.y));
            lm1.y = fmaxf(lm1.y, fmaxf(w.z, w.w));
        }
    }

    *(float2*)(M + (size_t)b * HW + 2 * t) = lm0;
    if (a1) *(float2*)(M + (size_t)b * HW + 2 * u1) = lm1;
}

// Block = (h, n-slice). 224 active threads = 28 cols x 8 image-phases.
__global__ __launch_bounds__(256) void k_out(const float* __restrict__ x,
                                             const float* __restrict__ M,
                                             float* __restrict__ out) {
    __shared__ float part[8][28];

    const int bid = blockIdx.x;
    const int h   = bid % 28;
    const int n0  = (bid / 28) * IPB2;
    const int t   = threadIdx.x;
    const int c   = t % 28;       // output col w
    const int g   = t / 28;       // phase / row-group
    const bool act = (t < 224);   // 8 full groups

    float p0[16];
    if (act) {
        // issue the x loads early; they ride under the M-reduce latency
        const float* xp = x + (size_t)(n0 + g) * IMG + h * 112 + c * 2;
#pragma unroll
        for (int k = 0; k < 16; ++k)
            p0[k] = xp[(size_t)(8 * k) * IMG];

        // reduce 64 rows of M for this col
        const float* mp = M + (size_t)(g * 64) * HW + h * 28 + c;
        float cm = 0.0f;
#pragma unroll 8
        for (int r = 0; r < 64; ++r)
            cm = fmaxf(cm, mp[(size_t)r * HW]);
        part[g][c] = cm;
    }

    __syncthreads();

    if (act) {
        float m = part[0][c];
#pragma unroll
        for (int g2 = 1; g2 < 8; ++g2) m = fmaxf(m, part[g2][c]);
        const float r = 0.5f / (m + 1e-8f);   // cos(pi*u) = v_cos(u*0.5) [revolutions]

        float* op = out + (size_t)(n0 + g) * HW + h * 28 + c;
#pragma unroll
        for (int k = 0; k < 16; ++k)
            op[(size_t)(8 * k) * HW] = __builtin_amdgcn_cosf(p0[k] * r);
    }
}

} // namespace

extern "C" void kernel_launch(void* const* d_in, const int* in_sizes, int n_in,
                              void* d_out, int out_size, void* d_ws, size_t ws_size,
                              hipStream_t stream) {
    const float* x   = (const float*)d_in[0];
    float*       M   = (float*)d_ws;           // 512*784 floats = 1.57 MB
    float*       out = (float*)d_out;

    hipLaunchKernelGGL(k_partial, dim3(NB1), dim3(256), 0, stream, x, M);
    hipLaunchKernelGGL(k_out, dim3(28 * NSL), dim3(256), 0, stream,
                       x, (const float*)M, out);
}